// Round 11
// baseline (1022.573 us; speedup 1.0000x reference)
//
#include <hip/hip_runtime.h>
#include <hip/hip_bf16.h>
#include <math.h>

#define NTOT 32768
#define HDIM 128
#define NE   524288
#define NGRAPH 32
#define NNODE 1024
#define NHEAD 4
#define DHEAD 32

typedef __attribute__((ext_vector_type(8))) short bf8v;
typedef __attribute__((ext_vector_type(4))) float f4v;
typedef unsigned short u16;

__device__ __forceinline__ float4 ld4(const float* p){ return *(const float4*)p; }

__device__ __forceinline__ u16 bf16rn(float f){
  union { float f; unsigned u; } x; x.f = f;
  unsigned r = x.u + 0x7FFF + ((x.u >> 16) & 1);
  return (u16)(r >> 16);
}
__device__ __forceinline__ unsigned pk2(float a, float b){
  unsigned r;
  asm("v_cvt_pk_bf16_f32 %0, %1, %2" : "=v"(r) : "v"(a), "v"(b));
  return r;
}
__device__ __forceinline__ float bf2f(u16 u){
  union { unsigned u; float f; } x; x.u = ((unsigned)u) << 16;
  return x.f;
}

// ---------------- CSR build ----------------
__global__ void k_count(const int* __restrict__ dst, int* __restrict__ deg){
  int e = blockIdx.x*256 + threadIdx.x;
  atomicAdd(&deg[dst[e]], 1);
}

__global__ __launch_bounds__(1024) void k_scan(const int* __restrict__ deg,
                                               int* __restrict__ indptr,
                                               int* __restrict__ cursor){
  __shared__ int sm[1024];
  int t = threadIdx.x;
  int base = t*32;
  int s = 0;
  for (int j=0;j<32;j++) s += deg[base+j];
  sm[t] = s; __syncthreads();
  for (int off=1; off<1024; off<<=1){
    int v = (t>=off) ? sm[t-off] : 0;
    __syncthreads();
    sm[t] += v;
    __syncthreads();
  }
  int ex = sm[t] - s;
  for (int j=0;j<32;j++){
    int d = deg[base+j];
    indptr[base+j] = ex; cursor[base+j] = ex;
    ex += d;
  }
  if (t == 1023) indptr[NTOT] = ex;
}

__global__ void k_fill(const int* __restrict__ dst, int* __restrict__ cursor,
                       int* __restrict__ epos){
  int e = blockIdx.x*256 + threadIdx.x;
  int pos = atomicAdd(&cursor[dst[e]], 1);
  epos[e] = pos;
}

// merged one-time prep
__global__ __launch_bounds__(256) void k_prep(const float* __restrict__ ea,
    const int* __restrict__ src, const int* __restrict__ epos,
    u16* __restrict__ EAb, int* __restrict__ SRCp,
    const float* __restrict__ x, u16* __restrict__ Xb,
    const float* s0,const float* s1,const float* s2,
    const float* s3,const float* s4,const float* s5, u16* __restrict__ Wb){
  int b = blockIdx.x, tid = threadIdx.x;
  if (b < 65536){
    int e = b*8 + (tid>>5);
    int c4 = (tid&31)*4;
    int pos = epos[e];
    float4 v = ld4(&ea[(size_t)e*HDIM + c4]);
    uint2 o; o.x = pk2(v.x, v.y); o.y = pk2(v.z, v.w);
    *(uint2*)&EAb[(size_t)pos*HDIM + c4] = o;
    if ((tid&31) == 0) SRCp[pos] = src[e];
  } else if (b < 69632){
    size_t i = ((size_t)(b-65536)*256 + tid)*4;
    float4 v = ld4(&x[i]);
    uint2 o; o.x = pk2(v.x,v.y); o.y = pk2(v.z,v.w);
    *(uint2*)&Xb[i] = o;
  } else {
    int idx = b - 69632;
    int y = idx / 144;
    int i = (idx % 144)*256 + tid;
    const float* srcs[6] = {s0,s1,s2,s3,s4,s5};
    const int cnt4[6] = {12288,12288,36864,12288,24576,24576};
    const int off[6]  = {0,49152,98304,245760,294912,393216};
    if (i < cnt4[y]){
      float4 v = ld4(&srcs[y][(size_t)i*4]);
      uint2 o; o.x = pk2(v.x,v.y); o.y = pk2(v.z,v.w);
      *(uint2*)&Wb[off[y] + (size_t)i*4] = o;
    }
  }
}

// ---------------- aggr body ----------------
__device__ __forceinline__ void aggr_body(int bx, int tid,
    const u16* __restrict__ Xb, const u16* __restrict__ EAb,
    const int* __restrict__ SRCp, const int* __restrict__ indptr,
    u16* __restrict__ Hb){
  int n = bx*8 + (tid>>5);
  int c4 = (tid&31)*4;
  int p0 = indptr[n], p1 = indptr[n+1];
  float a0=0.f,a1=0.f,a2=0.f,a3=0.f;
  int p = p0;
  int sNext = (p < p1) ? SRCp[p] : 0;
  for (; p<p1; p++){
    int s = sNext;
    if (p+1 < p1) sNext = SRCp[p+1];
    uint2 ev = *(const uint2*)&EAb[(size_t)p*HDIM + c4];
    uint2 xv = *(const uint2*)&Xb[(size_t)s*HDIM + c4];
    a0 += fmaxf(bf2f((u16)(xv.x&0xffff)) + bf2f((u16)(ev.x&0xffff)), 0.f);
    a1 += fmaxf(bf2f((u16)(xv.x>>16))    + bf2f((u16)(ev.x>>16)), 0.f);
    a2 += fmaxf(bf2f((u16)(xv.y&0xffff)) + bf2f((u16)(ev.y&0xffff)), 0.f);
    a3 += fmaxf(bf2f((u16)(xv.y>>16))    + bf2f((u16)(ev.y>>16)), 0.f);
  }
  uint2 xn = *(const uint2*)&Xb[(size_t)n*HDIM + c4];
  a0 += bf2f((u16)(xn.x&0xffff)); a1 += bf2f((u16)(xn.x>>16));
  a2 += bf2f((u16)(xn.y&0xffff)); a3 += bf2f((u16)(xn.y>>16));
  uint2 o; o.x = pk2(a0,a1); o.y = pk2(a2,a3);
  *(uint2*)&Hb[(size_t)n*HDIM + c4] = o;
}

// ---------------- LDS-free bf16 MFMA GEMM body: BM=128, BN=64 ----------------
template<bool BNA, bool DUAL, bool RELU, bool EP, bool STATS, bool WROUT>
__device__ __forceinline__ void bgemm_body(int bx, int by, int tid,
    const u16* __restrict__ Ab, const u16* __restrict__ A2b,
    const float* __restrict__ slotA, const float* __restrict__ gA, const float* __restrict__ bA,
    const float* __restrict__ slotB, const float* __restrict__ gB, const float* __restrict__ bB,
    const u16* __restrict__ Wb, const float* __restrict__ bias,
    const u16* __restrict__ Epb, u16* __restrict__ Cb,
    u16* __restrict__ OUTb, float* __restrict__ slotOut, int N, int K,
    float* sbn1, float* sbn2, float* sred){
  int w = tid>>6, l = tid&63;
  int q = l&15, g = l>>4;
  int m0 = bx*128, n0 = by*64;
  int wr = w*32;
  const float invn = 1.0f/32768.0f;
  if ((BNA || DUAL) && tid < 128){
    float mean = slotA[tid]*invn;
    float var  = slotA[128+tid]*invn - mean*mean;
    float s = gA[tid] * rsqrtf(var + 1e-5f);
    sbn1[tid] = s; sbn1[128+tid] = bA[tid] - mean*s;
    if (DUAL){
      float mean2 = slotB[tid]*invn;
      float var2  = slotB[128+tid]*invn - mean2*mean2;
      float s2 = gB[tid] * rsqrtf(var2 + 1e-5f);
      sbn2[tid] = s2; sbn2[128+tid] = bB[tid] - mean2*s2;
    }
  }
  if (STATS && tid < 128) sred[tid] = 0.f;
  if (BNA || DUAL || STATS) __syncthreads();

  f4v acc[2][4];
  #pragma unroll
  for (int i=0;i<2;i++)
    #pragma unroll
    for (int j=0;j<4;j++) acc[i][j] = (f4v){0.f,0.f,0.f,0.f};

  for (int kc=0; kc<K; kc+=32){
    bf8v af[2];
    #pragma unroll
    for (int mt=0;mt<2;mt++){
      int row = m0 + wr + 16*mt + q;
      if (!BNA && !DUAL){
        af[mt] = *(const bf8v*)&Ab[(size_t)row*K + kc + 8*g];
      } else {
        union { bf8v b; u16 s[8]; unsigned u[4]; } ra, r2, ro;
        ra.b = *(const bf8v*)&Ab[(size_t)row*K + kc + 8*g];
        if (DUAL) r2.b = *(const bf8v*)&A2b[(size_t)row*K + kc + 8*g];
        float v[8];
        #pragma unroll
        for (int j=0;j<8;j++){
          int kk = kc + 8*g + j;
          float f = bf2f(ra.s[j]) * sbn1[kk] + sbn1[128+kk];
          if (BNA) f = fmaxf(f, 0.f);
          if (DUAL) f += bf2f(r2.s[j]) * sbn2[kk] + sbn2[128+kk];
          v[j] = f;
        }
        ro.u[0]=pk2(v[0],v[1]); ro.u[1]=pk2(v[2],v[3]);
        ro.u[2]=pk2(v[4],v[5]); ro.u[3]=pk2(v[6],v[7]);
        af[mt] = ro.b;
        if (WROUT && by == 0)
          *(uint4*)&OUTb[(size_t)row*K + kc + 8*g] = *(uint4*)ro.u;
      }
    }
    bf8v bfv[4];
    #pragma unroll
    for (int nt=0;nt<4;nt++)
      bfv[nt] = *(const bf8v*)&Wb[(size_t)(n0+16*nt+q)*K + kc + 8*g];
    #pragma unroll
    for (int mt=0;mt<2;mt++)
      #pragma unroll
      for (int nt=0;nt<4;nt++)
        acc[mt][nt] = __builtin_amdgcn_mfma_f32_16x16x32_bf16(af[mt], bfv[nt], acc[mt][nt], 0,0,0);
  }
  float bbv[4];
  #pragma unroll
  for (int nt=0;nt<4;nt++) bbv[nt] = bias[n0 + 16*nt + q];
  float csum[4] = {0.f,0.f,0.f,0.f}, csq[4] = {0.f,0.f,0.f,0.f};
  #pragma unroll
  for (int mt=0;mt<2;mt++){
    int row0 = m0 + wr + 16*mt + 4*g;
    #pragma unroll
    for (int nt=0;nt<4;nt++){
      int col = n0 + 16*nt + q;
      #pragma unroll
      for (int r=0;r<4;r++){
        size_t off = (size_t)(row0+r)*N + col;
        float v = acc[mt][nt][r] + bbv[nt];
        if (EP) v += bf2f(Epb[off]);
        if (RELU) v = fmaxf(v, 0.f);
        Cb[off] = bf16rn(v);
        if (STATS){ csum[nt] += v; csq[nt] += v*v; }
      }
    }
  }
  if (STATS){
    #pragma unroll
    for (int nt=0;nt<4;nt++){
      int c = 16*nt + q;
      atomicAdd(&sred[c], csum[nt]);
      atomicAdd(&sred[64+c], csq[nt]);
    }
    __syncthreads();
    if (tid < 64){
      atomicAdd(&slotOut[n0+tid], sred[tid]);
      atomicAdd(&slotOut[128+n0+tid], sred[64+tid]);
    }
  }
}

// ---------------- QKV GEMM body ----------------
__device__ __forceinline__ void qkv_body(int bx, int by, int tid,
    const u16* __restrict__ Ab, const u16* __restrict__ Wb, const float* __restrict__ bias,
    u16* __restrict__ Qb, u16* __restrict__ Kb, u16* __restrict__ VT, u16* Sm){
  int w = tid>>6, l = tid&63;
  int q = l&15, g = l>>4;
  int which = by >> 1, half = by & 1;
  int m0 = bx*128, n0 = by*64;
  const int K = 128;
  int wr = w*32;
  f4v acc[2][4];
  #pragma unroll
  for (int i=0;i<2;i++)
    #pragma unroll
    for (int j=0;j<4;j++) acc[i][j] = (f4v){0.f,0.f,0.f,0.f};
  for (int kc=0; kc<K; kc+=32){
    bf8v af[2];
    #pragma unroll
    for (int mt=0;mt<2;mt++)
      af[mt] = *(const bf8v*)&Ab[(size_t)(m0+wr+16*mt+q)*K + kc + 8*g];
    bf8v bfv[4];
    #pragma unroll
    for (int nt=0;nt<4;nt++)
      bfv[nt] = *(const bf8v*)&Wb[(size_t)(n0+16*nt+q)*K + kc + 8*g];
    #pragma unroll
    for (int mt=0;mt<2;mt++)
      #pragma unroll
      for (int nt=0;nt<4;nt++)
        acc[mt][nt] = __builtin_amdgcn_mfma_f32_16x16x32_bf16(af[mt], bfv[nt], acc[mt][nt], 0,0,0);
  }
  const float QSC = 0.17677669529663687f * 1.4426950408889634f;
  float scale = (which==0) ? QSC : 1.0f;
  float bbv[4];
  #pragma unroll
  for (int nt=0;nt<4;nt++) bbv[nt] = bias[n0 + 16*nt + q];
  if (which < 2){
    #pragma unroll
    for (int mt=0;mt<2;mt++){
      int row0 = wr + 16*mt + 4*g;
      #pragma unroll
      for (int nt=0;nt<4;nt++){
        int c = 16*nt + q;
        #pragma unroll
        for (int r=0;r<4;r++)
          Sm[(row0+r)*72 + c] = bf16rn((acc[mt][nt][r] + bbv[nt]) * scale);
      }
    }
    __syncthreads();
    u16* dst = (which==0) ? Qb : Kb;
    #pragma unroll
    for (int it=0; it<4; it++){
      int idx = tid + it*256;
      int row = idx >> 3, c8 = (idx & 7) * 8;
      uint4 v = *(const uint4*)&Sm[row*72 + c8];
      *(uint4*)&dst[(size_t)(m0+row)*128 + half*64 + c8] = v;
    }
  } else {
    #pragma unroll
    for (int mt=0;mt<2;mt++){
      int row0 = wr + 16*mt + 4*g;
      #pragma unroll
      for (int nt=0;nt<4;nt++){
        int c = 16*nt + q;
        uint2 p;
        p.x = pk2(acc[mt][nt][0] + bbv[nt], acc[mt][nt][1] + bbv[nt]);
        p.y = pk2(acc[mt][nt][2] + bbv[nt], acc[mt][nt][3] + bbv[nt]);
        *(uint2*)&Sm[c*136 + row0] = p;
      }
    }
    __syncthreads();
    int gg = m0 >> 10;
    int nl0 = m0 & 1023;
    #pragma unroll
    for (int it=0; it<4; it++){
      int idx = tid + it*256;
      int c = idx >> 4, n8 = (idx & 15) * 8;
      uint4 v = *(const uint4*)&Sm[c*136 + n8];
      *(uint4*)&VT[((size_t)gg*128 + half*64 + c)*1024 + nl0 + n8] = v;
    }
  }
}

// ---------------- flash attention body (defer-max) ----------------
__device__ __forceinline__ void flash_body(int qt, int h, int g, int tid,
    const u16* __restrict__ Qb, const u16* __restrict__ Kb, const u16* __restrict__ VT,
    u16* __restrict__ O, u16* Pl){
  int w = tid >> 6, l = tid & 63;
  int q = l & 15, grp = l >> 4;
  size_t gbase = (size_t)g*1024;
  size_t qrow0 = gbase + qt*64 + w*16;
  const u16* Vp = VT + ((size_t)(g*4 + h)*32)*1024;
  bf8v qf = *(const bf8v*)&Qb[(qrow0 + q)*128 + h*32 + 8*grp];
  u16* Pw = Pl + w*(16*72);
  float m = -1e30f, lsum = 0.f;
  f4v o0 = {0.f,0.f,0.f,0.f}, o1 = {0.f,0.f,0.f,0.f};
  for (int kt=0; kt<16; kt++){
    int k0 = kt*64;
    f4v st[4];
    #pragma unroll
    for (int t=0;t<4;t++){
      bf8v kf = *(const bf8v*)&Kb[(gbase + k0 + 16*t + q)*128 + h*32 + 8*grp];
      st[t] = __builtin_amdgcn_mfma_f32_16x16x32_bf16(kf, qf, (f4v){0.f,0.f,0.f,0.f}, 0,0,0);
    }
    float smax = st[0][0];
    #pragma unroll
    for (int t=0;t<4;t++)
      #pragma unroll
      for (int r=0;r<4;r++) smax = fmaxf(smax, st[t][r]);
    smax = fmaxf(smax, __shfl_xor(smax, 16));
    smax = fmaxf(smax, __shfl_xor(smax, 32));
    bool need = __any(smax > m + 8.f);
    float mnew = m, alpha = 1.f;
    if (need){
      mnew = fmaxf(m, smax);
      alpha = exp2f(m - mnew);
    }
    float psum = 0.f;
    #pragma unroll
    for (int t=0;t<4;t++){
      float p0 = exp2f(st[t][0]-mnew), p1 = exp2f(st[t][1]-mnew);
      float p2 = exp2f(st[t][2]-mnew), p3 = exp2f(st[t][3]-mnew);
      psum += (p0+p1)+(p2+p3);
      *(unsigned*)&Pw[q*72 + 16*t + 4*grp]     = pk2(p0,p1);
      *(unsigned*)&Pw[q*72 + 16*t + 4*grp + 2] = pk2(p2,p3);
    }
    psum += __shfl_xor(psum, 16);
    psum += __shfl_xor(psum, 32);
    lsum = lsum*alpha + psum;
    m = mnew;
    if (need){
      f4v aD;
      #pragma unroll
      for (int r=0;r<4;r++) aD[r] = __shfl(alpha, 4*grp + r);
      #pragma unroll
      for (int r=0;r<4;r++){ o0[r] *= aD[r]; o1[r] *= aD[r]; }
    }
    bf8v pa0 = *(const bf8v*)&Pw[q*72 + 8*grp];
    bf8v pa1 = *(const bf8v*)&Pw[q*72 + 32 + 8*grp];
    bf8v v00 = *(const bf8v*)&Vp[(size_t)q*1024      + k0 + 8*grp];
    bf8v v01 = *(const bf8v*)&Vp[(size_t)q*1024      + k0 + 32 + 8*grp];
    bf8v v10 = *(const bf8v*)&Vp[(size_t)(16+q)*1024 + k0 + 8*grp];
    bf8v v11 = *(const bf8v*)&Vp[(size_t)(16+q)*1024 + k0 + 32 + 8*grp];
    o0 = __builtin_amdgcn_mfma_f32_16x16x32_bf16(pa0, v00, o0, 0,0,0);
    o0 = __builtin_amdgcn_mfma_f32_16x16x32_bf16(pa1, v01, o0, 0,0,0);
    o1 = __builtin_amdgcn_mfma_f32_16x16x32_bf16(pa0, v10, o1, 0,0,0);
    o1 = __builtin_amdgcn_mfma_f32_16x16x32_bf16(pa1, v11, o1, 0,0,0);
  }
  f4v lD;
  #pragma unroll
  for (int r=0;r<4;r++) lD[r] = __shfl(lsum, 4*grp + r);
  #pragma unroll
  for (int r=0;r<4;r++){
    float inv = 1.0f/lD[r];
    size_t row = qrow0 + 4*grp + r;
    O[row*HDIM + h*32 + q]      = bf16rn(o0[r]*inv);
    O[row*HDIM + h*32 + 16 + q] = bf16rn(o1[r]*inv);
  }
}

// ---------------- fused dispatches (INTERLEAVED block assignment) ----------------
// D1: 5632 = 512 periods of 11: r<8 -> aggr (512*8=4096), r>=8 -> qkv (512*3=1536)
__global__ __launch_bounds__(256) void k_d1(const u16* __restrict__ Xb,
    const u16* __restrict__ EAb, const int* __restrict__ SRCp, const int* __restrict__ indptr,
    u16* __restrict__ Hb,
    const u16* __restrict__ wq, const float* __restrict__ BQ,
    u16* __restrict__ Qb, u16* __restrict__ Kb, u16* __restrict__ VTb){
  __shared__ u16 Sm[128*72];
  int bx = blockIdx.x;
  int gPer = bx / 11, r = bx % 11;
  if (r < 8){
    aggr_body(gPer*8 + r, threadIdx.x, Xb, EAb, SRCp, indptr, Hb);
  } else {
    int b = gPer*3 + (r - 8);
    qkv_body(b & 255, b >> 8, threadIdx.x, Xb, wq, BQ, Qb, Kb, VTb, Sm);
  }
}

// D2: 2560 = 512 periods of 5: r<4 -> flash (2048), r==4 -> W1 (512)
__global__ __launch_bounds__(256) void k_d2(const u16* __restrict__ Qb,
    const u16* __restrict__ Kb, const u16* __restrict__ VTb, u16* __restrict__ Ob,
    const u16* __restrict__ Hb, const u16* __restrict__ w1, const float* __restrict__ B1,
    u16* __restrict__ G1, float* __restrict__ S0){
  __shared__ u16 Pl[4*16*72];
  __shared__ float sb1[256], sb2[256], sr[128];
  int bx = blockIdx.x;
  int gPer = bx / 5, r = bx % 5;
  if (r < 4){
    int f = gPer*4 + r;
    flash_body(f & 15, (f >> 4) & 3, f >> 6, threadIdx.x, Qb, Kb, VTb, Ob, Pl);
  } else {
    bgemm_body<false,false,false,false,true,false>(gPer & 255, gPer >> 8, threadIdx.x,
      Hb, nullptr, nullptr,nullptr,nullptr, nullptr,nullptr,nullptr,
      w1, B1, nullptr, G1, nullptr, S0, 128, 128, sb1, sb2, sr);
  }
}

// D3: 1024, even -> W2, odd -> WO
__global__ __launch_bounds__(256) void k_d3(const u16* __restrict__ G1,
    const float* __restrict__ S0, const float* __restrict__ bnG, const float* __restrict__ bnB,
    const u16* __restrict__ w2, const float* __restrict__ B2,
    const u16* __restrict__ Xb, u16* __restrict__ P1, float* __restrict__ S1,
    const u16* __restrict__ Ob, const u16* __restrict__ wo, const float* __restrict__ BO,
    u16* __restrict__ P2, float* __restrict__ S2){
  __shared__ float sb1[256], sb2[256], sr[128];
  int bx = blockIdx.x;
  int b = bx >> 1;
  if ((bx & 1) == 0){
    bgemm_body<true,false,false,true,true,false>(b & 255, b >> 8, threadIdx.x,
      G1, nullptr, S0, bnG, bnB, nullptr,nullptr,nullptr,
      w2, B2, Xb, P1, nullptr, S1, 128, 128, sb1, sb2, sr);
  } else {
    bgemm_body<false,false,false,true,true,false>(b & 255, b >> 8, threadIdx.x,
      Ob, nullptr, nullptr,nullptr,nullptr, nullptr,nullptr,nullptr,
      wo, BO, Xb, P2, nullptr, S2, 128, 128, sb1, sb2, sr);
  }
}

// ---------------- fused MLP: FF/OUT in LDS, BM=64, 512 blocks ----------------
__global__ __launch_bounds__(256) void k_mlpf(const u16* __restrict__ P1, const u16* __restrict__ P2,
    const float* __restrict__ S1, const float* __restrict__ n1g, const float* __restrict__ n1b,
    const float* __restrict__ S2, const float* __restrict__ n2g, const float* __restrict__ n2b,
    const u16* __restrict__ wm1, const float* __restrict__ BM1,
    const u16* __restrict__ wm2, const float* __restrict__ BM2,
    u16* __restrict__ H3, float* __restrict__ S3){
  __shared__ u16 FF[64][268];
  __shared__ u16 OUTs[64][138];
  __shared__ float sb1[256], sb2[256], sred[256];
  int tid = threadIdx.x;
  int w = tid>>6, l = tid&63;
  int q = l&15, g = l>>4;
  int m0 = blockIdx.x*64;
  const float invn = 1.0f/32768.0f;
  if (tid < 128){
    float mean = S1[tid]*invn;
    float var  = S1[128+tid]*invn - mean*mean;
    float s = n1g[tid] * rsqrtf(var + 1e-5f);
    sb1[tid] = s; sb1[128+tid] = n1b[tid] - mean*s;
    float mean2 = S2[tid]*invn;
    float var2  = S2[128+tid]*invn - mean2*mean2;
    float s2 = n2g[tid] * rsqrtf(var2 + 1e-5f);
    sb2[tid] = s2; sb2[128+tid] = n2b[tid] - mean2*s2;
    sred[tid] = 0.f; sred[128+tid] = 0.f;
  }
  __syncthreads();

  f4v acc1[16];
  #pragma unroll
  for (int j=0;j<16;j++) acc1[j] = (f4v){0.f,0.f,0.f,0.f};
  int lrow = w*16 + q;
  int row = m0 + lrow;
  for (int kc=0; kc<128; kc+=32){
    union { bf8v b; u16 s[8]; unsigned u[4]; } ra, r2, ro;
    ra.b = *(const bf8v*)&P1[(size_t)row*128 + kc + 8*g];
    r2.b = *(const bf8v*)&P2[(size_t)row*128 + kc + 8*g];
    float v[8];
    #pragma unroll
    for (int j=0;j<8;j++){
      int kk = kc + 8*g + j;
      v[j] = bf2f(ra.s[j]) * sb1[kk] + sb1[128+kk]
           + bf2f(r2.s[j]) * sb2[kk] + sb2[128+kk];
    }
    ro.u[0]=pk2(v[0],v[1]); ro.u[1]=pk2(v[2],v[3]);
    ro.u[2]=pk2(v[4],v[5]); ro.u[3]=pk2(v[6],v[7]);
    *(uint4*)&OUTs[lrow][kc + 8*g] = *(uint4*)ro.u;
    #pragma unroll
    for (int nt=0;nt<16;nt++){
      bf8v bv = *(const bf8v*)&wm1[(size_t)(16*nt+q)*128 + kc + 8*g];
      acc1[nt] = __builtin_amdgcn_mfma_f32_16x16x32_bf16(ro.b, bv, acc1[nt], 0,0,0);
    }
  }
  #pragma unroll
  for (int nt=0;nt<16;nt++){
    int col = 16*nt + q;
    float bb = BM1[col];
    int r0 = w*16 + 4*g;
    #pragma unroll
    for (int r=0;r<4;r++)
      FF[r0+r][col] = bf16rn(fmaxf(acc1[nt][r] + bb, 0.f));
  }
  __syncthreads();

  f4v acc2[8];
  #pragma unroll
  for (int j=0;j<8;j++) acc2[j] = (f4v){0.f,0.f,0.f,0.f};
  for (int kc=0; kc<256; kc+=32){
    bf8v af = *(const bf8v*)&FF[lrow][kc + 8*g];
    #pragma unroll
    for (int nt=0;nt<8;nt++){
      bf8v bv = *(const bf8v*)&wm2[(size_t)(16*nt+q)*256 + kc + 8*g];
      acc2[nt] = __builtin_amdgcn_mfma_f32_16x16x32_bf16(af, bv, acc2[nt], 0,0,0);
    }
  }
  float csum[8], csq[8];
  #pragma unroll
  for (int nt=0;nt<8;nt++){ csum[nt]=0.f; csq[nt]=0.f; }
  int r0 = w*16 + 4*g;
  #pragma unroll
  for (int nt=0;nt<8;nt++){
    int col = 16*nt + q;
    float bb = BM2[col];
    #pragma unroll
    for (int r=0;r<4;r++){
      float v = acc2[nt][r] + bb + bf2f(OUTs[r0+r][col]);
      H3[(size_t)(m0+r0+r)*128 + col] = bf16rn(v);
      csum[nt] += v; csq[nt] += v*v;
    }
  }
  #pragma unroll
  for (int nt=0;nt<8;nt++){
    int c = 16*nt + q;
    atomicAdd(&sred[c], csum[nt]);
    atomicAdd(&sred[128+c], csq[nt]);
  }
  __syncthreads();
  if (tid < 128){
    atomicAdd(&S3[tid], sred[tid]);
    atomicAdd(&S3[128+tid], sred[128+tid]);
  }
}

// ---------------- BN apply ----------------
template<bool RELU, bool F32OUT>
__global__ __launch_bounds__(256) void k_bnapply(const u16* __restrict__ X,
    const float* __restrict__ slot, const float* __restrict__ gv, const float* __restrict__ bv,
    u16* __restrict__ Yb, float* __restrict__ Yf){
  int idx = blockIdx.x*256 + threadIdx.x;
  int row = idx >> 4, c8 = (idx & 15) * 8;
  const float invn = 1.0f/32768.0f;
  union { uint4 u; u16 s[8]; } iv;
  iv.u = *(const uint4*)&X[(size_t)row*HDIM + c8];
  float o[8];
  #pragma unroll
  for (int j=0;j<8;j++){
    int c = c8+j;
    float mean = slot[c]*invn;
    float var  = slot[128+c]*invn - mean*mean;
    float sc = gv[c] * rsqrtf(var + 1e-5f);
    float sh = bv[c] - mean*sc;
    float v = bf2f(iv.s[j])*sc + sh;
    if (RELU) v = fmaxf(v, 0.f);
    o[j] = v;
  }
  if (F32OUT){
    float* dst = &Yf[(size_t)row*HDIM + c8];
    *(float4*)dst = make_float4(o[0],o[1],o[2],o[3]);
    *(float4*)(dst+4) = make_float4(o[4],o[5],o[6],o[7]);
  } else {
    uint4 ov;
    ov.x = pk2(o[0],o[1]); ov.y = pk2(o[2],o[3]);
    ov.z = pk2(o[4],o[5]); ov.w = pk2(o[6],o[7]);
    *(uint4*)&Yb[(size_t)row*HDIM + c8] = ov;
  }
}

// ---------------- host ----------------
extern "C" void kernel_launch(void* const* d_in, const int* in_sizes, int n_in,
                              void* d_out, int out_size, void* d_ws, size_t ws_size,
                              hipStream_t stream){
  const float* x_in      = (const float*)d_in[0];
  const float* edge_attr = (const float*)d_in[1];
  const float* gine_w1   = (const float*)d_in[2];
  const float* gine_b1   = (const float*)d_in[3];
  const float* gine_bn_g = (const float*)d_in[4];
  const float* gine_bn_b = (const float*)d_in[5];
  const float* gine_w2   = (const float*)d_in[6];
  const float* gine_b2   = (const float*)d_in[7];
  const float* attn_wqkv = (const float*)d_in[8];
  const float* attn_bqkv = (const float*)d_in[9];
  const float* attn_wo   = (const float*)d_in[10];
  const float* attn_bo   = (const float*)d_in[11];
  const float* norm1_g   = (const float*)d_in[12];
  const float* norm1_b   = (const float*)d_in[13];
  const float* norm2_g   = (const float*)d_in[14];
  const float* norm2_b   = (const float*)d_in[15];
  const float* norm3_g   = (const float*)d_in[16];
  const float* norm3_b   = (const float*)d_in[17];
  const float* mlp_w1    = (const float*)d_in[18];
  const float* mlp_b1    = (const float*)d_in[19];
  const float* mlp_w2    = (const float*)d_in[20];
  const float* mlp_b2    = (const float*)d_in[21];
  const int* edge_index  = (const int*)d_in[22];
  const int* srcp = edge_index;
  const int* dstp = edge_index + NE;
  float* out = (float*)d_out;

  float* ws = (float*)d_ws;
  const size_t U = 4194304;            // 16 MB in floats
  u16* Xb   = (u16*)(ws);
  u16* Hb   = (u16*)(ws + U/2);
  u16* G1   = (u16*)(ws + U);
  u16* P1   = (u16*)(ws + U + U/2);
  u16* P2   = (u16*)(ws + 2*U);
  u16* Ob   = (u16*)(ws + 2*U + U/2);
  u16* H3   = (u16*)(ws + 3*U);
  u16* Qb   = (u16*)(ws + 5*U);
  u16* Kb   = (u16*)(ws + 5*U + U/2);
  u16* VTb  = (u16*)(ws + 6*U);
  u16* Wball= (u16*)(ws + 6*U + U/2);  // 983 KB
  float* STATS = ws + 7*U - 8192;      // 12 slots x 512 floats
  int* IW      = (int*)(ws + 7*U);
  int* deg     = IW;
  int* indptr  = IW + 32768;
  int* cursor  = IW + 32768 + 32772;
  int* epos    = cursor + 32768;       // NE ints
  u16* EAb  = (u16*)(ws + 8*U);        // 128 MB
  int* SRCp = (int*)(ws + 16*U);       // 2 MB

  u16* W1b  = Wball + 0;
  u16* W2b  = Wball + 49152;
  u16* WQb  = Wball + 98304;
  u16* WOb  = Wball + 245760;
  u16* WM1b = Wball + 294912;
  u16* WM2b = Wball + 393216;

  hipMemsetAsync(STATS, 0, 8192*sizeof(float) + NTOT*sizeof(int), stream);
  k_count<<<NE/256, 256, 0, stream>>>(dstp, deg);
  k_scan<<<1, 1024, 0, stream>>>(deg, indptr, cursor);
  k_fill<<<NE/256, 256, 0, stream>>>(dstp, cursor, epos);
  k_prep<<<70496, 256, 0, stream>>>(edge_attr, srcp, epos, EAb, SRCp, x_in, Xb,
                                    gine_w1, gine_w2, attn_wqkv, attn_wo, mlp_w1, mlp_w2, Wball);

  for (int i=0;i<3;i++){
    const float* B1 = gine_b1 + (size_t)i*HDIM;
    const float* B2 = gine_b2 + (size_t)i*HDIM;
    const float* BQ = attn_bqkv + (size_t)i*3*HDIM;
    const float* BO = attn_bo + (size_t)i*HDIM;
    const float* BM1 = mlp_b1 + (size_t)i*2*HDIM;
    const float* BM2 = mlp_b2 + (size_t)i*HDIM;
    u16* w1 = W1b + (size_t)i*16384;
    u16* w2 = W2b + (size_t)i*16384;
    u16* wq = WQb + (size_t)i*49152;
    u16* wo = WOb + (size_t)i*16384;
    u16* wm1 = WM1b + (size_t)i*32768;
    u16* wm2 = WM2b + (size_t)i*32768;
    float* S0 = STATS + (size_t)(i*4+0)*512;
    float* S1 = STATS + (size_t)(i*4+1)*512;
    float* S2 = STATS + (size_t)(i*4+2)*512;
    float* S3 = STATS + (size_t)(i*4+3)*512;
    const float* bnG = gine_bn_g + (size_t)i*HDIM;
    const float* bnB = gine_bn_b + (size_t)i*HDIM;
    const float* n1g = norm1_g + (size_t)i*HDIM, *n1b = norm1_b + (size_t)i*HDIM;
    const float* n2g = norm2_g + (size_t)i*HDIM, *n2b = norm2_b + (size_t)i*HDIM;
    const float* n3g = norm3_g + (size_t)i*HDIM, *n3b = norm3_b + (size_t)i*HDIM;

    // D1: aggr || QKV (interleaved)
    k_d1<<<5632, 256, 0, stream>>>(Xb, EAb, SRCp, indptr, Hb, wq, BQ, Qb, Kb, VTb);
    // D2: flash || W1 (interleaved, stats S0)
    k_d2<<<2560, 256, 0, stream>>>(Qb, Kb, VTb, Ob, Hb, w1, B1, G1, S0);
    // D3: W2 || WO (interleaved)
    k_d3<<<1024, 256, 0, stream>>>(G1, S0, bnG, bnB, w2, B2, Xb, P1, S1,
                                   Ob, wo, BO, P2, S2);
    // fused MLP
    k_mlpf<<<512, 256, 0, stream>>>(P1, P2, S1, n1g, n1b, S2, n2g, n2b,
                                    wm1, BM1, wm2, BM2, H3, S3);

    if (i<2) k_bnapply<true ,false><<<2048, 256, 0, stream>>>(H3, S3, n3g, n3b, Xb, nullptr);
    else     k_bnapply<false,true ><<<2048, 256, 0, stream>>>(H3, S3, n3g, n3b, nullptr, out);
  }
}

// Round 13
// 977.013 us; speedup vs baseline: 1.0466x; 1.0466x over previous
//
#include <hip/hip_runtime.h>
#include <hip/hip_bf16.h>
#include <math.h>

#define NTOT 32768
#define HDIM 128
#define NE   524288
#define NGRAPH 32
#define NNODE 1024
#define NHEAD 4
#define DHEAD 32

typedef __attribute__((ext_vector_type(8))) short bf8v;
typedef __attribute__((ext_vector_type(4))) float f4v;
typedef unsigned short u16;

__device__ __forceinline__ float4 ld4(const float* p){ return *(const float4*)p; }

__device__ __forceinline__ u16 bf16rn(float f){
  union { float f; unsigned u; } x; x.f = f;
  unsigned r = x.u + 0x7FFF + ((x.u >> 16) & 1);
  return (u16)(r >> 16);
}
__device__ __forceinline__ unsigned pk2(float a, float b){
  unsigned r;
  asm("v_cvt_pk_bf16_f32 %0, %1, %2" : "=v"(r) : "v"(a), "v"(b));
  return r;
}
__device__ __forceinline__ float bf2f(u16 u){
  union { unsigned u; float f; } x; x.u = ((unsigned)u) << 16;
  return x.f;
}

// ---------------- CSR build ----------------
__global__ void k_count(const int* __restrict__ dst, int* __restrict__ deg){
  int e = blockIdx.x*256 + threadIdx.x;
  atomicAdd(&deg[dst[e]], 1);
}

__global__ __launch_bounds__(1024) void k_scan(const int* __restrict__ deg,
                                               int* __restrict__ indptr,
                                               int* __restrict__ cursor){
  __shared__ int sm[1024];
  int t = threadIdx.x;
  int base = t*32;
  int s = 0;
  for (int j=0;j<32;j++) s += deg[base+j];
  sm[t] = s; __syncthreads();
  for (int off=1; off<1024; off<<=1){
    int v = (t>=off) ? sm[t-off] : 0;
    __syncthreads();
    sm[t] += v;
    __syncthreads();
  }
  int ex = sm[t] - s;
  for (int j=0;j<32;j++){
    int d = deg[base+j];
    indptr[base+j] = ex; cursor[base+j] = ex;
    ex += d;
  }
  if (t == 1023) indptr[NTOT] = ex;
}

__global__ void k_fill(const int* __restrict__ dst, int* __restrict__ cursor,
                       int* __restrict__ epos){
  int e = blockIdx.x*256 + threadIdx.x;
  int pos = atomicAdd(&cursor[dst[e]], 1);
  epos[e] = pos;
}

// merged one-time prep
__global__ __launch_bounds__(256) void k_prep(const float* __restrict__ ea,
    const int* __restrict__ src, const int* __restrict__ epos,
    u16* __restrict__ EAb, int* __restrict__ SRCp,
    const float* __restrict__ x, u16* __restrict__ Xb,
    const float* s0,const float* s1,const float* s2,
    const float* s3,const float* s4,const float* s5, u16* __restrict__ Wb){
  int b = blockIdx.x, tid = threadIdx.x;
  if (b < 65536){
    int e = b*8 + (tid>>5);
    int c4 = (tid&31)*4;
    int pos = epos[e];
    float4 v = ld4(&ea[(size_t)e*HDIM + c4]);
    uint2 o; o.x = pk2(v.x, v.y); o.y = pk2(v.z, v.w);
    *(uint2*)&EAb[(size_t)pos*HDIM + c4] = o;
    if ((tid&31) == 0) SRCp[pos] = src[e];
  } else if (b < 69632){
    size_t i = ((size_t)(b-65536)*256 + tid)*4;
    float4 v = ld4(&x[i]);
    uint2 o; o.x = pk2(v.x,v.y); o.y = pk2(v.z,v.w);
    *(uint2*)&Xb[i] = o;
  } else {
    int idx = b - 69632;
    int y = idx / 144;
    int i = (idx % 144)*256 + tid;
    const float* srcs[6] = {s0,s1,s2,s3,s4,s5};
    const int cnt4[6] = {12288,12288,36864,12288,24576,24576};
    const int off[6]  = {0,49152,98304,245760,294912,393216};
    if (i < cnt4[y]){
      float4 v = ld4(&srcs[y][(size_t)i*4]);
      uint2 o; o.x = pk2(v.x,v.y); o.y = pk2(v.z,v.w);
      *(uint2*)&Wb[off[y] + (size_t)i*4] = o;
    }
  }
}

// ---------------- aggr body ----------------
__device__ __forceinline__ void aggr_body(int bx, int tid,
    const u16* __restrict__ Xb, const u16* __restrict__ EAb,
    const int* __restrict__ SRCp, const int* __restrict__ indptr,
    u16* __restrict__ Hb){
  int n = bx*8 + (tid>>5);
  int c4 = (tid&31)*4;
  int p0 = indptr[n], p1 = indptr[n+1];
  float a0=0.f,a1=0.f,a2=0.f,a3=0.f;
  int p = p0;
  int sNext = (p < p1) ? SRCp[p] : 0;
  for (; p<p1; p++){
    int s = sNext;
    if (p+1 < p1) sNext = SRCp[p+1];
    uint2 ev = *(const uint2*)&EAb[(size_t)p*HDIM + c4];
    uint2 xv = *(const uint2*)&Xb[(size_t)s*HDIM + c4];
    a0 += fmaxf(bf2f((u16)(xv.x&0xffff)) + bf2f((u16)(ev.x&0xffff)), 0.f);
    a1 += fmaxf(bf2f((u16)(xv.x>>16))    + bf2f((u16)(ev.x>>16)), 0.f);
    a2 += fmaxf(bf2f((u16)(xv.y&0xffff)) + bf2f((u16)(ev.y&0xffff)), 0.f);
    a3 += fmaxf(bf2f((u16)(xv.y>>16))    + bf2f((u16)(ev.y>>16)), 0.f);
  }
  uint2 xn = *(const uint2*)&Xb[(size_t)n*HDIM + c4];
  a0 += bf2f((u16)(xn.x&0xffff)); a1 += bf2f((u16)(xn.x>>16));
  a2 += bf2f((u16)(xn.y&0xffff)); a3 += bf2f((u16)(xn.y>>16));
  uint2 o; o.x = pk2(a0,a1); o.y = pk2(a2,a3);
  *(uint2*)&Hb[(size_t)n*HDIM + c4] = o;
}

// ---------------- LDS-free bf16 MFMA GEMM body: BM=128, BN=64 ----------------
template<bool BNA, bool DUAL, bool RELU, bool EP, bool STATS, bool WROUT>
__device__ __forceinline__ void bgemm_body(int bx, int by, int tid,
    const u16* __restrict__ Ab, const u16* __restrict__ A2b,
    const float* __restrict__ slotA, const float* __restrict__ gA, const float* __restrict__ bA,
    const float* __restrict__ slotB, const float* __restrict__ gB, const float* __restrict__ bB,
    const u16* __restrict__ Wb, const float* __restrict__ bias,
    const u16* __restrict__ Epb, u16* __restrict__ Cb,
    u16* __restrict__ OUTb, float* __restrict__ slotOut, int N, int K,
    float* sbn1, float* sbn2, float* sred){
  int w = tid>>6, l = tid&63;
  int q = l&15, g = l>>4;
  int m0 = bx*128, n0 = by*64;
  int wr = w*32;
  const float invn = 1.0f/32768.0f;
  if ((BNA || DUAL) && tid < 128){
    float mean = slotA[tid]*invn;
    float var  = slotA[128+tid]*invn - mean*mean;
    float s = gA[tid] * rsqrtf(var + 1e-5f);
    sbn1[tid] = s; sbn1[128+tid] = bA[tid] - mean*s;
    if (DUAL){
      float mean2 = slotB[tid]*invn;
      float var2  = slotB[128+tid]*invn - mean2*mean2;
      float s2 = gB[tid] * rsqrtf(var2 + 1e-5f);
      sbn2[tid] = s2; sbn2[128+tid] = bB[tid] - mean2*s2;
    }
  }
  if (STATS && tid < 128) sred[tid] = 0.f;
  if (BNA || DUAL || STATS) __syncthreads();

  f4v acc[2][4];
  #pragma unroll
  for (int i=0;i<2;i++)
    #pragma unroll
    for (int j=0;j<4;j++) acc[i][j] = (f4v){0.f,0.f,0.f,0.f};

  for (int kc=0; kc<K; kc+=32){
    bf8v af[2];
    #pragma unroll
    for (int mt=0;mt<2;mt++){
      int row = m0 + wr + 16*mt + q;
      if (!BNA && !DUAL){
        af[mt] = *(const bf8v*)&Ab[(size_t)row*K + kc + 8*g];
      } else {
        union { bf8v b; u16 s[8]; unsigned u[4]; } ra, r2, ro;
        ra.b = *(const bf8v*)&Ab[(size_t)row*K + kc + 8*g];
        if (DUAL) r2.b = *(const bf8v*)&A2b[(size_t)row*K + kc + 8*g];
        float v[8];
        #pragma unroll
        for (int j=0;j<8;j++){
          int kk = kc + 8*g + j;
          float f = bf2f(ra.s[j]) * sbn1[kk] + sbn1[128+kk];
          if (BNA) f = fmaxf(f, 0.f);
          if (DUAL) f += bf2f(r2.s[j]) * sbn2[kk] + sbn2[128+kk];
          v[j] = f;
        }
        ro.u[0]=pk2(v[0],v[1]); ro.u[1]=pk2(v[2],v[3]);
        ro.u[2]=pk2(v[4],v[5]); ro.u[3]=pk2(v[6],v[7]);
        af[mt] = ro.b;
        if (WROUT && by == 0)
          *(uint4*)&OUTb[(size_t)row*K + kc + 8*g] = *(uint4*)ro.u;
      }
    }
    bf8v bfv[4];
    #pragma unroll
    for (int nt=0;nt<4;nt++)
      bfv[nt] = *(const bf8v*)&Wb[(size_t)(n0+16*nt+q)*K + kc + 8*g];
    #pragma unroll
    for (int mt=0;mt<2;mt++)
      #pragma unroll
      for (int nt=0;nt<4;nt++)
        acc[mt][nt] = __builtin_amdgcn_mfma_f32_16x16x32_bf16(af[mt], bfv[nt], acc[mt][nt], 0,0,0);
  }
  float bbv[4];
  #pragma unroll
  for (int nt=0;nt<4;nt++) bbv[nt] = bias[n0 + 16*nt + q];
  float csum[4] = {0.f,0.f,0.f,0.f}, csq[4] = {0.f,0.f,0.f,0.f};
  #pragma unroll
  for (int mt=0;mt<2;mt++){
    int row0 = m0 + wr + 16*mt + 4*g;
    #pragma unroll
    for (int nt=0;nt<4;nt++){
      int col = n0 + 16*nt + q;
      #pragma unroll
      for (int r=0;r<4;r++){
        size_t off = (size_t)(row0+r)*N + col;
        float v = acc[mt][nt][r] + bbv[nt];
        if (EP) v += bf2f(Epb[off]);
        if (RELU) v = fmaxf(v, 0.f);
        Cb[off] = bf16rn(v);
        if (STATS){ csum[nt] += v; csq[nt] += v*v; }
      }
    }
  }
  if (STATS){
    #pragma unroll
    for (int nt=0;nt<4;nt++){
      int c = 16*nt + q;
      atomicAdd(&sred[c], csum[nt]);
      atomicAdd(&sred[64+c], csq[nt]);
    }
    __syncthreads();
    if (tid < 64){
      atomicAdd(&slotOut[n0+tid], sred[tid]);
      atomicAdd(&slotOut[128+n0+tid], sred[64+tid]);
    }
  }
}

// ---------------- QKV GEMM body ----------------
__device__ __forceinline__ void qkv_body(int bx, int by, int tid,
    const u16* __restrict__ Ab, const u16* __restrict__ Wb, const float* __restrict__ bias,
    u16* __restrict__ Qb, u16* __restrict__ Kb, u16* __restrict__ VT, u16* Sm){
  int w = tid>>6, l = tid&63;
  int q = l&15, g = l>>4;
  int which = by >> 1, half = by & 1;
  int m0 = bx*128, n0 = by*64;
  const int K = 128;
  int wr = w*32;
  f4v acc[2][4];
  #pragma unroll
  for (int i=0;i<2;i++)
    #pragma unroll
    for (int j=0;j<4;j++) acc[i][j] = (f4v){0.f,0.f,0.f,0.f};
  for (int kc=0; kc<K; kc+=32){
    bf8v af[2];
    #pragma unroll
    for (int mt=0;mt<2;mt++)
      af[mt] = *(const bf8v*)&Ab[(size_t)(m0+wr+16*mt+q)*K + kc + 8*g];
    bf8v bfv[4];
    #pragma unroll
    for (int nt=0;nt<4;nt++)
      bfv[nt] = *(const bf8v*)&Wb[(size_t)(n0+16*nt+q)*K + kc + 8*g];
    #pragma unroll
    for (int mt=0;mt<2;mt++)
      #pragma unroll
      for (int nt=0;nt<4;nt++)
        acc[mt][nt] = __builtin_amdgcn_mfma_f32_16x16x32_bf16(af[mt], bfv[nt], acc[mt][nt], 0,0,0);
  }
  const float QSC = 0.17677669529663687f * 1.4426950408889634f;
  float scale = (which==0) ? QSC : 1.0f;
  float bbv[4];
  #pragma unroll
  for (int nt=0;nt<4;nt++) bbv[nt] = bias[n0 + 16*nt + q];
  if (which < 2){
    #pragma unroll
    for (int mt=0;mt<2;mt++){
      int row0 = wr + 16*mt + 4*g;
      #pragma unroll
      for (int nt=0;nt<4;nt++){
        int c = 16*nt + q;
        #pragma unroll
        for (int r=0;r<4;r++)
          Sm[(row0+r)*72 + c] = bf16rn((acc[mt][nt][r] + bbv[nt]) * scale);
      }
    }
    __syncthreads();
    u16* dst = (which==0) ? Qb : Kb;
    #pragma unroll
    for (int it=0; it<4; it++){
      int idx = tid + it*256;
      int row = idx >> 3, c8 = (idx & 7) * 8;
      uint4 v = *(const uint4*)&Sm[row*72 + c8];
      *(uint4*)&dst[(size_t)(m0+row)*128 + half*64 + c8] = v;
    }
  } else {
    #pragma unroll
    for (int mt=0;mt<2;mt++){
      int row0 = wr + 16*mt + 4*g;
      #pragma unroll
      for (int nt=0;nt<4;nt++){
        int c = 16*nt + q;
        uint2 p;
        p.x = pk2(acc[mt][nt][0] + bbv[nt], acc[mt][nt][1] + bbv[nt]);
        p.y = pk2(acc[mt][nt][2] + bbv[nt], acc[mt][nt][3] + bbv[nt]);
        *(uint2*)&Sm[c*136 + row0] = p;
      }
    }
    __syncthreads();
    int gg = m0 >> 10;
    int nl0 = m0 & 1023;
    #pragma unroll
    for (int it=0; it<4; it++){
      int idx = tid + it*256;
      int c = idx >> 4, n8 = (idx & 15) * 8;
      uint4 v = *(const uint4*)&Sm[c*136 + n8];
      *(uint4*)&VT[((size_t)gg*128 + half*64 + c)*1024 + nl0 + n8] = v;
    }
  }
}

// ---------------- flash attention body v4: 32-row q-tile, key-split wave pairs ----------------
// wave w: rh=w&1 -> 16-row half; kh=w>>1 -> 512-key half (8 kt). Exact merge via LDS.
// NOTE: m/alpha/lsum are PER-Q-ROW (lane's q=l&15); o rows are 4*grp+r -> shfl broadcasts.
__device__ __forceinline__ void flash_body(int qt, int h, int g, int tid,
    const u16* __restrict__ Qb, const u16* __restrict__ Kb, const u16* __restrict__ VT,
    u16* __restrict__ O, u16* Pl, float* Om, float* Ml){
  int w = tid >> 6, l = tid & 63;
  int q = l & 15, grp = l >> 4;
  int rh = w & 1, kh = w >> 1;
  size_t gbase = (size_t)g*1024;
  size_t qrow0 = gbase + qt*32 + rh*16;
  const u16* Vp = VT + ((size_t)(g*4 + h)*32)*1024;
  bf8v qf = *(const bf8v*)&Qb[(qrow0 + q)*128 + h*32 + 8*grp];
  u16* Pw = Pl + w*(16*72);
  float* Omw = Om + w*(16*32);
  float* Mlw = Ml + w*32;
  float m = -1e30f, lsum = 0.f;
  f4v o0 = {0.f,0.f,0.f,0.f}, o1 = {0.f,0.f,0.f,0.f};
  int kt0 = kh*8;
  bf8v kf0, kf1, kf2, kf3;
  {
    int k0 = kt0*64;
    kf0 = *(const bf8v*)&Kb[(gbase + k0 +  0 + q)*128 + h*32 + 8*grp];
    kf1 = *(const bf8v*)&Kb[(gbase + k0 + 16 + q)*128 + h*32 + 8*grp];
    kf2 = *(const bf8v*)&Kb[(gbase + k0 + 32 + q)*128 + h*32 + 8*grp];
    kf3 = *(const bf8v*)&Kb[(gbase + k0 + 48 + q)*128 + h*32 + 8*grp];
  }
  for (int it=0; it<8; it++){
    int k0 = (kt0+it)*64;
    bf8v v00 = *(const bf8v*)&Vp[(size_t)q*1024      + k0 + 8*grp];
    bf8v v01 = *(const bf8v*)&Vp[(size_t)q*1024      + k0 + 32 + 8*grp];
    bf8v v10 = *(const bf8v*)&Vp[(size_t)(16+q)*1024 + k0 + 8*grp];
    bf8v v11 = *(const bf8v*)&Vp[(size_t)(16+q)*1024 + k0 + 32 + 8*grp];
    f4v st[4];
    st[0] = __builtin_amdgcn_mfma_f32_16x16x32_bf16(kf0, qf, (f4v){0.f,0.f,0.f,0.f}, 0,0,0);
    st[1] = __builtin_amdgcn_mfma_f32_16x16x32_bf16(kf1, qf, (f4v){0.f,0.f,0.f,0.f}, 0,0,0);
    st[2] = __builtin_amdgcn_mfma_f32_16x16x32_bf16(kf2, qf, (f4v){0.f,0.f,0.f,0.f}, 0,0,0);
    st[3] = __builtin_amdgcn_mfma_f32_16x16x32_bf16(kf3, qf, (f4v){0.f,0.f,0.f,0.f}, 0,0,0);
    if (it < 7){
      int kn = k0 + 64;
      kf0 = *(const bf8v*)&Kb[(gbase + kn +  0 + q)*128 + h*32 + 8*grp];
      kf1 = *(const bf8v*)&Kb[(gbase + kn + 16 + q)*128 + h*32 + 8*grp];
      kf2 = *(const bf8v*)&Kb[(gbase + kn + 32 + q)*128 + h*32 + 8*grp];
      kf3 = *(const bf8v*)&Kb[(gbase + kn + 48 + q)*128 + h*32 + 8*grp];
    }
    float ma = fmaxf(fmaxf(st[0][0],st[0][1]), fmaxf(st[0][2],st[0][3]));
    float mb = fmaxf(fmaxf(st[1][0],st[1][1]), fmaxf(st[1][2],st[1][3]));
    float mc = fmaxf(fmaxf(st[2][0],st[2][1]), fmaxf(st[2][2],st[2][3]));
    float md = fmaxf(fmaxf(st[3][0],st[3][1]), fmaxf(st[3][2],st[3][3]));
    float smax = fmaxf(fmaxf(ma,mb), fmaxf(mc,md));
    smax = fmaxf(smax, __shfl_xor(smax, 16));
    smax = fmaxf(smax, __shfl_xor(smax, 32));
    bool need = __any(smax > m + 8.f);
    float mnew = m, alpha = 1.f;
    if (need){
      mnew = fmaxf(m, smax);
      alpha = exp2f(m - mnew);
    }
    float psum = 0.f;
    #pragma unroll
    for (int t=0;t<4;t++){
      float p0 = exp2f(st[t][0]-mnew), p1 = exp2f(st[t][1]-mnew);
      float p2 = exp2f(st[t][2]-mnew), p3 = exp2f(st[t][3]-mnew);
      psum += (p0+p1)+(p2+p3);
      *(unsigned*)&Pw[q*72 + 16*t + 4*grp]     = pk2(p0,p1);
      *(unsigned*)&Pw[q*72 + 16*t + 4*grp + 2] = pk2(p2,p3);
    }
    psum += __shfl_xor(psum, 16);
    psum += __shfl_xor(psum, 32);
    lsum = lsum*alpha + psum;
    m = mnew;
    if (need){
      f4v aD;
      #pragma unroll
      for (int r=0;r<4;r++) aD[r] = __shfl(alpha, 4*grp + r);
      #pragma unroll
      for (int r=0;r<4;r++){ o0[r] *= aD[r]; o1[r] *= aD[r]; }
    }
    bf8v pa0 = *(const bf8v*)&Pw[q*72 + 8*grp];
    bf8v pa1 = *(const bf8v*)&Pw[q*72 + 32 + 8*grp];
    o0 = __builtin_amdgcn_mfma_f32_16x16x32_bf16(pa0, v00, o0, 0,0,0);
    o0 = __builtin_amdgcn_mfma_f32_16x16x32_bf16(pa1, v01, o0, 0,0,0);
    o1 = __builtin_amdgcn_mfma_f32_16x16x32_bf16(pa0, v10, o1, 0,0,0);
    o1 = __builtin_amdgcn_mfma_f32_16x16x32_bf16(pa1, v11, o1, 0,0,0);
  }
  // ---- exact merge of the two key-halves (per-q-row m and l) ----
  if (grp == 0){ Mlw[q] = lsum; Mlw[16+q] = m; }
  #pragma unroll
  for (int r=0;r<4;r++){
    Omw[(4*grp+r)*32 + q]      = o0[r];
    Omw[(4*grp+r)*32 + 16 + q] = o1[r];
  }
  __syncthreads();
  if (kh == 0){
    const float* Mlo = Ml + (w+2)*32;
    const float* Omo = Om + (w+2)*(16*32);
    float m_ot = Mlo[16+q];
    float l_ot = Mlo[q];
    float mstar = fmaxf(m, m_ot);
    float a_me = exp2f(m - mstar), a_ot = exp2f(m_ot - mstar);
    float lstar = lsum*a_me + l_ot*a_ot;
    f4v aMe, aOt, lD;
    #pragma unroll
    for (int r=0;r<4;r++){
      aMe[r] = __shfl(a_me, 4*grp + r);
      aOt[r] = __shfl(a_ot, 4*grp + r);
      lD[r]  = __shfl(lstar, 4*grp + r);
    }
    #pragma unroll
    for (int r=0;r<4;r++){
      float v0 = o0[r]*aMe[r] + Omo[(4*grp+r)*32 + q]*aOt[r];
      float v1 = o1[r]*aMe[r] + Omo[(4*grp+r)*32 + 16 + q]*aOt[r];
      float inv = 1.0f/lD[r];
      size_t row = qrow0 + 4*grp + r;
      O[row*HDIM + h*32 + q]      = bf16rn(v0*inv);
      O[row*HDIM + h*32 + 16 + q] = bf16rn(v1*inv);
    }
  }
}

// ---------------- fused dispatches ----------------
// D1: [0,4096) aggr ; [4096,5632) qkv
__global__ __launch_bounds__(256) void k_d1(const u16* __restrict__ Xb,
    const u16* __restrict__ EAb, const int* __restrict__ SRCp, const int* __restrict__ indptr,
    u16* __restrict__ Hb,
    const u16* __restrict__ wq, const float* __restrict__ BQ,
    u16* __restrict__ Qb, u16* __restrict__ Kb, u16* __restrict__ VTb){
  __shared__ u16 Sm[128*72];
  int bx = blockIdx.x;
  if (bx < 4096){
    aggr_body(bx, threadIdx.x, Xb, EAb, SRCp, indptr, Hb);
  } else {
    int b = bx - 4096;
    qkv_body(b & 255, b >> 8, threadIdx.x, Xb, wq, BQ, Qb, Kb, VTb, Sm);
  }
}

// D2: [0,4096) flash (32-row tiles, key-split) ; [4096,4608) W1 gemm (stats S0)
__global__ __launch_bounds__(256,4) void k_d2(const u16* __restrict__ Qb,
    const u16* __restrict__ Kb, const u16* __restrict__ VTb, u16* __restrict__ Ob,
    const u16* __restrict__ Hb, const u16* __restrict__ w1, const float* __restrict__ B1,
    u16* __restrict__ G1, float* __restrict__ S0){
  __shared__ u16 Pl[4*16*72];
  __shared__ float Om[4*16*32];
  __shared__ float Ml[4*32];
  __shared__ float sb1[256], sb2[256], sr[128];
  int bx = blockIdx.x;
  if (bx < 4096){
    int qt = bx & 31, h = (bx >> 5) & 3, g = bx >> 7;
    flash_body(qt, h, g, threadIdx.x, Qb, Kb, VTb, Ob, Pl, Om, Ml);
  } else {
    int b = bx - 4096;
    bgemm_body<false,false,false,false,true,false>(b & 255, b >> 8, threadIdx.x,
      Hb, nullptr, nullptr,nullptr,nullptr, nullptr,nullptr,nullptr,
      w1, B1, nullptr, G1, nullptr, S0, 128, 128, sb1, sb2, sr);
  }
}

// D3: [0,512) W2 gemm ; [512,1024) WO gemm
__global__ __launch_bounds__(256) void k_d3(const u16* __restrict__ G1,
    const float* __restrict__ S0, const float* __restrict__ bnG, const float* __restrict__ bnB,
    const u16* __restrict__ w2, const float* __restrict__ B2,
    const u16* __restrict__ Xb, u16* __restrict__ P1, float* __restrict__ S1,
    const u16* __restrict__ Ob, const u16* __restrict__ wo, const float* __restrict__ BO,
    u16* __restrict__ P2, float* __restrict__ S2){
  __shared__ float sb1[256], sb2[256], sr[128];
  int bx = blockIdx.x;
  if (bx < 512){
    bgemm_body<true,false,false,true,true,false>(bx & 255, bx >> 8, threadIdx.x,
      G1, nullptr, S0, bnG, bnB, nullptr,nullptr,nullptr,
      w2, B2, Xb, P1, nullptr, S1, 128, 128, sb1, sb2, sr);
  } else {
    int b = bx - 512;
    bgemm_body<false,false,false,true,true,false>(b & 255, b >> 8, threadIdx.x,
      Ob, nullptr, nullptr,nullptr,nullptr, nullptr,nullptr,nullptr,
      wo, BO, Xb, P2, nullptr, S2, 128, 128, sb1, sb2, sr);
  }
}

// ---------------- fused MLP: FF/OUT in LDS, BM=64, 512 blocks ----------------
__global__ __launch_bounds__(256) void k_mlpf(const u16* __restrict__ P1, const u16* __restrict__ P2,
    const float* __restrict__ S1, const float* __restrict__ n1g, const float* __restrict__ n1b,
    const float* __restrict__ S2, const float* __restrict__ n2g, const float* __restrict__ n2b,
    const u16* __restrict__ wm1, const float* __restrict__ BM1,
    const u16* __restrict__ wm2, const float* __restrict__ BM2,
    u16* __restrict__ H3, float* __restrict__ S3){
  __shared__ u16 FF[64][268];
  __shared__ u16 OUTs[64][138];
  __shared__ float sb1[256], sb2[256], sred[256];
  int tid = threadIdx.x;
  int w = tid>>6, l = tid&63;
  int q = l&15, g = l>>4;
  int m0 = blockIdx.x*64;
  const float invn = 1.0f/32768.0f;
  if (tid < 128){
    float mean = S1[tid]*invn;
    float var  = S1[128+tid]*invn - mean*mean;
    float s = n1g[tid] * rsqrtf(var + 1e-5f);
    sb1[tid] = s; sb1[128+tid] = n1b[tid] - mean*s;
    float mean2 = S2[tid]*invn;
    float var2  = S2[128+tid]*invn - mean2*mean2;
    float s2 = n2g[tid] * rsqrtf(var2 + 1e-5f);
    sb2[tid] = s2; sb2[128+tid] = n2b[tid] - mean2*s2;
    sred[tid] = 0.f; sred[128+tid] = 0.f;
  }
  __syncthreads();

  f4v acc1[16];
  #pragma unroll
  for (int j=0;j<16;j++) acc1[j] = (f4v){0.f,0.f,0.f,0.f};
  int lrow = w*16 + q;
  int row = m0 + lrow;
  for (int kc=0; kc<128; kc+=32){
    union { bf8v b; u16 s[8]; unsigned u[4]; } ra, r2, ro;
    ra.b = *(const bf8v*)&P1[(size_t)row*128 + kc + 8*g];
    r2.b = *(const bf8v*)&P2[(size_t)row*128 + kc + 8*g];
    float v[8];
    #pragma unroll
    for (int j=0;j<8;j++){
      int kk = kc + 8*g + j;
      v[j] = bf2f(ra.s[j]) * sb1[kk] + sb1[128+kk]
           + bf2f(r2.s[j]) * sb2[kk] + sb2[128+kk];
    }
    ro.u[0]=pk2(v[0],v[1]); ro.u[1]=pk2(v[2],v[3]);
    ro.u[2]=pk2(v[4],v[5]); ro.u[3]=pk2(v[6],v[7]);
    *(uint4*)&OUTs[lrow][kc + 8*g] = *(uint4*)ro.u;
    #pragma unroll
    for (int nt=0;nt<16;nt++){
      bf8v bv = *(const bf8v*)&wm1[(size_t)(16*nt+q)*128 + kc + 8*g];
      acc1[nt] = __builtin_amdgcn_mfma_f32_16x16x32_bf16(ro.b, bv, acc1[nt], 0,0,0);
    }
  }
  #pragma unroll
  for (int nt=0;nt<16;nt++){
    int col = 16*nt + q;
    float bb = BM1[col];
    int r0 = w*16 + 4*g;
    #pragma unroll
    for (int r=0;r<4;r++)
      FF[r0+r][col] = bf16rn(fmaxf(acc1[nt][r] + bb, 0.f));
  }
  __syncthreads();

  f4v acc2[8];
  #pragma unroll
  for (int j=0;j<8;j++) acc2[j] = (f4v){0.f,0.f,0.f,0.f};
  for (int kc=0; kc<256; kc+=32){
    bf8v af = *(const bf8v*)&FF[lrow][kc + 8*g];
    #pragma unroll
    for (int nt=0;nt<8;nt++){
      bf8v bv = *(const bf8v*)&wm2[(size_t)(16*nt+q)*256 + kc + 8*g];
      acc2[nt] = __builtin_amdgcn_mfma_f32_16x16x32_bf16(af, bv, acc2[nt], 0,0,0);
    }
  }
  float csum[8], csq[8];
  #pragma unroll
  for (int nt=0;nt<8;nt++){ csum[nt]=0.f; csq[nt]=0.f; }
  int r0 = w*16 + 4*g;
  #pragma unroll
  for (int nt=0;nt<8;nt++){
    int col = 16*nt + q;
    float bb = BM2[col];
    #pragma unroll
    for (int r=0;r<4;r++){
      float v = acc2[nt][r] + bb + bf2f(OUTs[r0+r][col]);
      H3[(size_t)(m0+r0+r)*128 + col] = bf16rn(v);
      csum[nt] += v; csq[nt] += v*v;
    }
  }
  #pragma unroll
  for (int nt=0;nt<8;nt++){
    int c = 16*nt + q;
    atomicAdd(&sred[c], csum[nt]);
    atomicAdd(&sred[128+c], csq[nt]);
  }
  __syncthreads();
  if (tid < 128){
    atomicAdd(&S3[tid], sred[tid]);
    atomicAdd(&S3[128+tid], sred[128+tid]);
  }
}

// ---------------- BN apply ----------------
template<bool RELU, bool F32OUT>
__global__ __launch_bounds__(256) void k_bnapply(const u16* __restrict__ X,
    const float* __restrict__ slot, const float* __restrict__ gv, const float* __restrict__ bv,
    u16* __restrict__ Yb, float* __restrict__ Yf){
  int idx = blockIdx.x*256 + threadIdx.x;
  int row = idx >> 4, c8 = (idx & 15) * 8;
  const float invn = 1.0f/32768.0f;
  union { uint4 u; u16 s[8]; } iv;
  iv.u = *(const uint4*)&X[(size_t)row*HDIM + c8];
  float o[8];
  #pragma unroll
  for (int j=0;j<8;j++){
    int c = c8+j;
    float mean = slot[c]*invn;
    float var  = slot[128+c]*invn - mean*mean;
    float sc = gv[c] * rsqrtf(var + 1e-5f);
    float sh = bv[c] - mean*sc;
    float v = bf2f(iv.s[j])*sc + sh;
    if (RELU) v = fmaxf(v, 0.f);
    o[j] = v;
  }
  if (F32OUT){
    float* dst = &Yf[(size_t)row*HDIM + c8];
    *(float4*)dst = make_float4(o[0],o[1],o[2],o[3]);
    *(float4*)(dst+4) = make_float4(o[4],o[5],o[6],o[7]);
  } else {
    uint4 ov;
    ov.x = pk2(o[0],o[1]); ov.y = pk2(o[2],o[3]);
    ov.z = pk2(o[4],o[5]); ov.w = pk2(o[6],o[7]);
    *(uint4*)&Yb[(size_t)row*HDIM + c8] = ov;
  }
}

// ---------------- host ----------------
extern "C" void kernel_launch(void* const* d_in, const int* in_sizes, int n_in,
                              void* d_out, int out_size, void* d_ws, size_t ws_size,
                              hipStream_t stream){
  const float* x_in      = (const float*)d_in[0];
  const float* edge_attr = (const float*)d_in[1];
  const float* gine_w1   = (const float*)d_in[2];
  const float* gine_b1   = (const float*)d_in[3];
  const float* gine_bn_g = (const float*)d_in[4];
  const float* gine_bn_b = (const float*)d_in[5];
  const float* gine_w2   = (const float*)d_in[6];
  const float* gine_b2   = (const float*)d_in[7];
  const float* attn_wqkv = (const float*)d_in[8];
  const float* attn_bqkv = (const float*)d_in[9];
  const float* attn_wo   = (const float*)d_in[10];
  const float* attn_bo   = (const float*)d_in[11];
  const float* norm1_g   = (const float*)d_in[12];
  const float* norm1_b   = (const float*)d_in[13];
  const float* norm2_g   = (const float*)d_in[14];
  const float* norm2_b   = (const float*)d_in[15];
  const float* norm3_g   = (const float*)d_in[16];
  const float* norm3_b   = (const float*)d_in[17];
  const float* mlp_w1    = (const float*)d_in[18];
  const float* mlp_b1    = (const float*)d_in[19];
  const float* mlp_w2    = (const float*)d_in[20];
  const float* mlp_b2    = (const float*)d_in[21];
  const int* edge_index  = (const int*)d_in[22];
  const int* srcp = edge_index;
  const int* dstp = edge_index + NE;
  float* out = (float*)d_out;

  float* ws = (float*)d_ws;
  const size_t U = 4194304;            // 16 MB in floats
  u16* Xb   = (u16*)(ws);
  u16* Hb   = (u16*)(ws + U/2);
  u16* G1   = (u16*)(ws + U);
  u16* P1   = (u16*)(ws + U + U/2);
  u16* P2   = (u16*)(ws + 2*U);
  u16* Ob   = (u16*)(ws + 2*U + U/2);
  u16* H3   = (u16*)(ws + 3*U);
  u16* Qb   = (u16*)(ws + 5*U);
  u16* Kb   = (u16*)(ws + 5*U + U/2);
  u16* VTb  = (u16*)(ws + 6*U);
  u16* Wball= (u16*)(ws + 6*U + U/2);  // 983 KB
  float* STATS = ws + 7*U - 8192;      // 12 slots x 512 floats
  int* IW      = (int*)(ws + 7*U);
  int* deg     = IW;
  int* indptr  = IW + 32768;
  int* cursor  = IW + 32768 + 32772;
  int* epos    = cursor + 32768;       // NE ints
  u16* EAb  = (u16*)(ws + 8*U);        // 128 MB
  int* SRCp = (int*)(ws + 16*U);       // 2 MB

  u16* W1b  = Wball + 0;
  u16* W2b  = Wball + 49152;
  u16* WQb  = Wball + 98304;
  u16* WOb  = Wball + 245760;
  u16* WM1b = Wball + 294912;
  u16* WM2b = Wball + 393216;

  hipMemsetAsync(STATS, 0, 8192*sizeof(float) + NTOT*sizeof(int), stream);
  k_count<<<NE/256, 256, 0, stream>>>(dstp, deg);
  k_scan<<<1, 1024, 0, stream>>>(deg, indptr, cursor);
  k_fill<<<NE/256, 256, 0, stream>>>(dstp, cursor, epos);
  k_prep<<<70496, 256, 0, stream>>>(edge_attr, srcp, epos, EAb, SRCp, x_in, Xb,
                                    gine_w1, gine_w2, attn_wqkv, attn_wo, mlp_w1, mlp_w2, Wball);

  for (int i=0;i<3;i++){
    const float* B1 = gine_b1 + (size_t)i*HDIM;
    const float* B2 = gine_b2 + (size_t)i*HDIM;
    const float* BQ = attn_bqkv + (size_t)i*3*HDIM;
    const float* BO = attn_bo + (size_t)i*HDIM;
    const float* BM1 = mlp_b1 + (size_t)i*2*HDIM;
    const float* BM2 = mlp_b2 + (size_t)i*HDIM;
    u16* w1 = W1b + (size_t)i*16384;
    u16* w2 = W2b + (size_t)i*16384;
    u16* wq = WQb + (size_t)i*49152;
    u16* wo = WOb + (size_t)i*16384;
    u16* wm1 = WM1b + (size_t)i*32768;
    u16* wm2 = WM2b + (size_t)i*32768;
    float* S0 = STATS + (size_t)(i*4+0)*512;
    float* S1 = STATS + (size_t)(i*4+1)*512;
    float* S2 = STATS + (size_t)(i*4+2)*512;
    float* S3 = STATS + (size_t)(i*4+3)*512;
    const float* bnG = gine_bn_g + (size_t)i*HDIM;
    const float* bnB = gine_bn_b + (size_t)i*HDIM;
    const float* n1g = norm1_g + (size_t)i*HDIM, *n1b = norm1_b + (size_t)i*HDIM;
    const float* n2g = norm2_g + (size_t)i*HDIM, *n2b = norm2_b + (size_t)i*HDIM;
    const float* n3g = norm3_g + (size_t)i*HDIM, *n3b = norm3_b + (size_t)i*HDIM;

    // D1: aggr || QKV
    k_d1<<<5632, 256, 0, stream>>>(Xb, EAb, SRCp, indptr, Hb, wq, BQ, Qb, Kb, VTb);
    // D2: flash (4096 blocks, 32-row tiles, key-split) || W1 (stats S0)
    k_d2<<<4608, 256, 0, stream>>>(Qb, Kb, VTb, Ob, Hb, w1, B1, G1, S0);
    // D3: W2 (+x, stats S1) || WO (+x, stats S2)
    k_d3<<<1024, 256, 0, stream>>>(G1, S0, bnG, bnB, w2, B2, Xb, P1, S1,
                                   Ob, wo, BO, P2, S2);
    // fused MLP
    k_mlpf<<<512, 256, 0, stream>>>(P1, P2, S1, n1g, n1b, S2, n2g, n2b,
                                    wm1, BM1, wm2, BM2, H3, S3);

    if (i<2) k_bnapply<true ,false><<<2048, 256, 0, stream>>>(H3, S3, n3g, n3b, Xb, nullptr);
    else     k_bnapply<false,true ><<<2048, 256, 0, stream>>>(H3, S3, n3g, n3b, nullptr, out);
  }
}